// Round 2
// baseline (315.134 us; speedup 1.0000x reference)
//
#include <hip/hip_runtime.h>
#include <hip/hip_bf16.h>

typedef float f32x4 __attribute__((ext_vector_type(4)));
typedef short s16x8 __attribute__((ext_vector_type(8)));
typedef unsigned short u16x4 __attribute__((ext_vector_type(4)));

__device__ __forceinline__ float bf2f(unsigned short u) {
    union { unsigned int i; float f; } x; x.i = ((unsigned int)u) << 16; return x.f;
}
__device__ __forceinline__ unsigned short f2bf(float f) {
    union { float f; unsigned int i; } x; x.f = f;
    unsigned int r = x.i + 0x7FFFu + ((x.i >> 16) & 1u);
    return (unsigned short)(r >> 16);
}
__device__ __forceinline__ float silu(float v) {
    return v / (1.f + __expf(-v));
}

#define GLDS16(gp, lp) __builtin_amdgcn_global_load_lds( \
    (const __attribute__((address_space(1))) unsigned int*)(gp), \
    (__attribute__((address_space(3))) unsigned int*)(lp), 16, 0, 0)

// ---------------------------------------------------------------------------
// Kernel 0: convert X / W_uvqk / W_o to bf16 (one pass, memory-bound)
// ---------------------------------------------------------------------------
__global__ __launch_bounds__(256) void cvt_bf16(
    const float* __restrict__ X, const float* __restrict__ W,
    const float* __restrict__ Wo,
    unsigned short* __restrict__ Xb, unsigned short* __restrict__ Wb,
    unsigned short* __restrict__ Wob)
{
    int idx = blockIdx.x * 256 + threadIdx.x;   // f32x4 chunk id, 2097152 total
    const float* src; unsigned short* dst; int off;
    if (idx < 1048576)       { src = X;  dst = Xb;  off = idx; }
    else if (idx < 1835008)  { src = W;  dst = Wb;  off = idx - 1048576; }
    else                     { src = Wo; dst = Wob; off = idx - 1835008; }
    f32x4 v = *reinterpret_cast<const f32x4*>(&src[(size_t)off * 4]);
    u16x4 o;
    #pragma unroll
    for (int j = 0; j < 4; ++j) o[j] = f2bf(v[j]);
    *reinterpret_cast<u16x4*>(&dst[(size_t)off * 4]) = o;
}

// ---------------------------------------------------------------------------
// Kernel 1: bucketize relative time -> byte matrix BK[b][i][j] (causal tiles)
// ---------------------------------------------------------------------------
__global__ __launch_bounds__(256) void bucketize(
    const int* __restrict__ TS, unsigned char* __restrict__ BK)
{
    const int jt = blockIdx.x, it = blockIdx.y, b = blockIdx.z;
    if (jt > it) return;                        // causal only
    __shared__ int bndRaw[63];
    __shared__ int bnd[64];
    __shared__ int tsi[64], tsj[64];
    const int tid = threadIdx.x;
    if (tid < 63) {
        double step = log(7776000.0) / 62.0;    // MAX_SPAN = 86400*90
        double v = exp(step * (double)tid);
        if (v < 1.0) v = 1.0;
        bndRaw[tid] = (int)floor(v);
    }
    if (tid >= 64 && tid < 128) tsi[tid - 64] = TS[b * 2048 + it * 64 + (tid - 64)];
    else if (tid >= 128 && tid < 192) tsj[tid - 128] = TS[b * 2048 + jt * 64 + (tid - 128)];
    __syncthreads();
    if (tid == 0) {                             // unique()
        int c = 0, p = -1;
        for (int i = 0; i < 63; ++i) { int x = bndRaw[i]; if (x != p) { bnd[c++] = x; p = x; } }
        for (; c < 64; ++c) bnd[c] = 0x7FFFFFFF;
    }
    __syncthreads();
    const int il = tid & 63, jc = (tid >> 6) * 16;
    const int tiv = tsi[il];
    unsigned char out[16];
    #pragma unroll
    for (int u = 0; u < 16; ++u) {
        int td = tiv - tsj[jc + u]; td = td < 0 ? -td : td; if (td < 1) td = 1;
        int pos = 0;
        #pragma unroll
        for (int st = 32; st; st >>= 1)
            if (bnd[pos + st - 1] < td) pos += st;
        out[u] = (unsigned char)pos;
    }
    *reinterpret_cast<int4*>(&BK[((size_t)b << 22) + (size_t)(it * 64 + il) * 2048 + jt * 64 + jc]) =
        *reinterpret_cast<const int4*>(out);
}

// ---------------------------------------------------------------------------
// Kernel 2: h = silu(Xb @ Wb^T + b); route into U, Vt, Q(*scale), K
// m97 structure: 128x128 tile, BK=32, global_load_lds width-16, linear LDS
// ---------------------------------------------------------------------------
__global__ __launch_bounds__(256) void gemm_uvqk(
    const unsigned short* __restrict__ Xb, const unsigned short* __restrict__ Wb,
    const float* __restrict__ bias,
    unsigned short* __restrict__ U, unsigned short* __restrict__ Vt,
    unsigned short* __restrict__ Q, unsigned short* __restrict__ K)
{
    __shared__ unsigned short sA[128][32];
    __shared__ unsigned short sB[128][32];
    const int tid = threadIdx.x;
    const int wv = tid >> 6, lane = tid & 63;
    const int g = lane >> 4, lr = lane & 15;
    const int m0 = blockIdx.x * 128, n0 = blockIdx.y * 128;
    const int wr = (wv >> 1) * 64, wc = (wv & 1) * 64;
    const int srow = (lane >> 2), scol = (lane & 3) * 8;   // staging lane layout
    f32x4 acc[4][4] = {};

    for (int k0 = 0; k0 < 1024; k0 += 32) {
        #pragma unroll
        for (int c = 0; c < 2; ++c) {
            int rb = (wv * 2 + c) * 16;
            GLDS16(&Xb[(size_t)(m0 + rb + srow) * 1024 + k0 + scol], &sA[rb][0]);
            GLDS16(&Wb[(size_t)(n0 + rb + srow) * 1024 + k0 + scol], &sB[rb][0]);
        }
        __syncthreads();
        s16x8 afr[4], bfr[4];
        #pragma unroll
        for (int i = 0; i < 4; ++i)
            afr[i] = *reinterpret_cast<const s16x8*>(&sA[wr + i * 16 + lr][g * 8]);
        #pragma unroll
        for (int i = 0; i < 4; ++i)
            bfr[i] = *reinterpret_cast<const s16x8*>(&sB[wc + i * 16 + lr][g * 8]);
        #pragma unroll
        for (int mi = 0; mi < 4; ++mi)
            #pragma unroll
            for (int ni = 0; ni < 4; ++ni)
                acc[mi][ni] = __builtin_amdgcn_mfma_f32_16x16x32_bf16(
                    afr[mi], bfr[ni], acc[mi][ni], 0, 0, 0);
        __syncthreads();
    }

    #pragma unroll
    for (int ni = 0; ni < 4; ++ni) {
        int n = n0 + wc + ni * 16 + lr;
        float bn = bias[n];
        #pragma unroll
        for (int mi = 0; mi < 4; ++mi) {
            #pragma unroll
            for (int r = 0; r < 4; ++r) {
                int m = m0 + wr + mi * 16 + g * 4 + r;
                float v = silu(acc[mi][ni][r] + bn);
                int b = m >> 11, l = m & 2047;
                if (n < 1024) {
                    U[(size_t)m * 1024 + n] = f2bf(v);
                } else if (n < 2048) {
                    int dd = n - 1024, h = dd >> 7, d = dd & 127;
                    Vt[(((size_t)(b * 8 + h) * 128 + d) << 11) + l] = f2bf(v);
                } else if (n < 2560) {
                    int dd = n - 2048, h = dd >> 6, d = dd & 63;
                    Q[((((size_t)(b * 8 + h) << 11) + l) << 6) + d] = f2bf(v * 0.125f);
                } else {
                    int dd = n - 2560, h = dd >> 6, d = dd & 63;
                    K[((((size_t)(b * 8 + h) << 11) + l) << 6) + d] = f2bf(v);
                }
            }
        }
    }
}

// ---------------------------------------------------------------------------
// Kernel 3: pointwise-silu attention, bias via precomputed BK byte matrix.
// 512 thr = 8 waves: waves 0-3 -> tile bx, waves 4-7 -> tile 31-bx (balanced).
// No barriers in the j-loop; waves fully independent.
// ---------------------------------------------------------------------------
__global__ __launch_bounds__(512) void attn(
    const unsigned short* __restrict__ Q, const unsigned short* __restrict__ K,
    const unsigned short* __restrict__ Vt, const unsigned char* __restrict__ BK,
    const float* __restrict__ TB, float* __restrict__ Y)
{
    __shared__ float tb[64];
    __shared__ unsigned short sP[8][16][72];

    const int tid = threadIdx.x, wv = tid >> 6, lane = tid & 63;
    const int g = lane >> 4, lr = lane & 15;
    const int bh = blockIdx.y, b = bh >> 3, h = bh & 7;

    if (tid < 64) tb[tid] = TB[tid * 8 + h];
    __syncthreads();

    const unsigned short* qb = Q + ((size_t)bh << 11) * 64;
    const unsigned short* kb = K + ((size_t)bh << 11) * 64;
    const unsigned short* vtb = Vt + ((size_t)bh << 7) * 2048;
    const unsigned char* bkb = BK + ((size_t)b << 22);

    const int ti = (wv < 4) ? (int)blockIdx.x : 31 - (int)blockIdx.x;
    const int ws = wv & 3;
    const int irow = ti * 64 + ws * 16;

    s16x8 aq[2];
    #pragma unroll
    for (int kk = 0; kk < 2; ++kk)
        aq[kk] = *reinterpret_cast<const s16x8*>(&qb[(size_t)(irow + lr) * 64 + kk * 32 + g * 8]);

    const unsigned char* bkr[4];
    #pragma unroll
    for (int r = 0; r < 4; ++r) bkr[r] = bkb + (size_t)(irow + g * 4 + r) * 2048;

    f32x4 accy[8] = {};
    for (int jt = 0; jt <= ti; ++jt) {
        const int j0 = jt * 64;
        // prefetch bias (byte load + LDS lookup), independent of MFMA chain
        float bias[4][4];
        #pragma unroll
        for (int ni = 0; ni < 4; ++ni)
            #pragma unroll
            for (int r = 0; r < 4; ++r)
                bias[ni][r] = tb[bkr[r][j0 + ni * 16 + lr]];
        f32x4 s[4] = {};
        #pragma unroll
        for (int ni = 0; ni < 4; ++ni) {
            #pragma unroll
            for (int kk = 0; kk < 2; ++kk) {
                s16x8 bk = *reinterpret_cast<const s16x8*>(
                    &kb[(size_t)(j0 + ni * 16 + lr) * 64 + kk * 32 + g * 8]);
                s[ni] = __builtin_amdgcn_mfma_f32_16x16x32_bf16(aq[kk], bk, s[ni], 0, 0, 0);
            }
        }
        #pragma unroll
        for (int ni = 0; ni < 4; ++ni) {
            int j = j0 + ni * 16 + lr;
            #pragma unroll
            for (int r = 0; r < 4; ++r) {
                int i = irow + g * 4 + r;
                float v = silu(s[ni][r] + bias[ni][r]);
                if (j > i) v = 0.f;             // only bites on the diagonal tile
                sP[wv][g * 4 + r][ni * 16 + lr] = f2bf(v);
            }
        }
        s16x8 apv[2];
        #pragma unroll
        for (int kk = 0; kk < 2; ++kk)
            apv[kk] = *reinterpret_cast<const s16x8*>(&sP[wv][lr][kk * 32 + g * 8]);
        #pragma unroll
        for (int di = 0; di < 8; ++di) {
            #pragma unroll
            for (int kk = 0; kk < 2; ++kk) {
                s16x8 bv = *reinterpret_cast<const s16x8*>(
                    &vtb[(size_t)(di * 16 + lr) * 2048 + j0 + kk * 32 + g * 8]);
                accy[di] = __builtin_amdgcn_mfma_f32_16x16x32_bf16(apv[kk], bv, accy[di], 0, 0, 0);
            }
        }
    }
    #pragma unroll
    for (int di = 0; di < 8; ++di)
        #pragma unroll
        for (int r = 0; r < 4; ++r) {
            int i = irow + g * 4 + r;
            Y[(size_t)((b << 11) + i) * 1024 + h * 128 + di * 16 + lr] = accy[di][r];
        }
}

// ---------------------------------------------------------------------------
// Kernel 4: RMSNorm over HID=1024 then U-gate; emit bf16 YP.
// ---------------------------------------------------------------------------
__global__ __launch_bounds__(256) void rmsnorm_gate(
    const float* __restrict__ Y, const unsigned short* __restrict__ U,
    const float* __restrict__ rw, unsigned short* __restrict__ YP)
{
    __shared__ float red[4];
    const int row = blockIdx.x, tid = threadIdx.x;
    f32x4 v = *reinterpret_cast<const f32x4*>(&Y[(size_t)row * 1024 + tid * 4]);
    float ss = v[0] * v[0] + v[1] * v[1] + v[2] * v[2] + v[3] * v[3];
    #pragma unroll
    for (int off = 32; off; off >>= 1) ss += __shfl_down(ss, off);
    if ((tid & 63) == 0) red[tid >> 6] = ss;
    __syncthreads();
    float rms = rsqrtf((red[0] + red[1] + red[2] + red[3]) * (1.f / 1024.f) + 1e-6f);
    #pragma unroll
    for (int j = 0; j < 4; ++j) {
        int c = tid * 4 + j;
        float o = v[j] * rms * rw[c] * bf2f(U[(size_t)row * 1024 + c]);
        YP[(size_t)row * 1024 + c] = f2bf(o);
    }
}

// ---------------------------------------------------------------------------
// Kernel 5: OUT = YP @ Wob^T + b_o.  Same m97 staging.
// ---------------------------------------------------------------------------
__global__ __launch_bounds__(256) void gemm_out(
    const unsigned short* __restrict__ YP, const unsigned short* __restrict__ Wob,
    const float* __restrict__ bo, float* __restrict__ OUT)
{
    __shared__ unsigned short sA[128][32];
    __shared__ unsigned short sB[128][32];
    const int tid = threadIdx.x;
    const int wv = tid >> 6, lane = tid & 63;
    const int g = lane >> 4, lr = lane & 15;
    const int m0 = blockIdx.x * 128, n0 = blockIdx.y * 128;
    const int wr = (wv >> 1) * 64, wc = (wv & 1) * 64;
    const int srow = (lane >> 2), scol = (lane & 3) * 8;
    f32x4 acc[4][4] = {};

    for (int k0 = 0; k0 < 1024; k0 += 32) {
        #pragma unroll
        for (int c = 0; c < 2; ++c) {
            int rb = (wv * 2 + c) * 16;
            GLDS16(&YP[(size_t)(m0 + rb + srow) * 1024 + k0 + scol], &sA[rb][0]);
            GLDS16(&Wob[(size_t)(n0 + rb + srow) * 1024 + k0 + scol], &sB[rb][0]);
        }
        __syncthreads();
        s16x8 afr[4], bfr[4];
        #pragma unroll
        for (int i = 0; i < 4; ++i)
            afr[i] = *reinterpret_cast<const s16x8*>(&sA[wr + i * 16 + lr][g * 8]);
        #pragma unroll
        for (int i = 0; i < 4; ++i)
            bfr[i] = *reinterpret_cast<const s16x8*>(&sB[wc + i * 16 + lr][g * 8]);
        #pragma unroll
        for (int mi = 0; mi < 4; ++mi)
            #pragma unroll
            for (int ni = 0; ni < 4; ++ni)
                acc[mi][ni] = __builtin_amdgcn_mfma_f32_16x16x32_bf16(
                    afr[mi], bfr[ni], acc[mi][ni], 0, 0, 0);
        __syncthreads();
    }

    #pragma unroll
    for (int ni = 0; ni < 4; ++ni) {
        int n = n0 + wc + ni * 16 + lr;
        float bn = bo[n];
        #pragma unroll
        for (int mi = 0; mi < 4; ++mi)
            #pragma unroll
            for (int r = 0; r < 4; ++r) {
                int m = m0 + wr + mi * 16 + g * 4 + r;
                OUT[(size_t)m * 1024 + n] = acc[mi][ni][r] + bn;
            }
    }
}

// ---------------------------------------------------------------------------
extern "C" void kernel_launch(void* const* d_in, const int* in_sizes, int n_in,
                              void* d_out, int out_size, void* d_ws, size_t ws_size,
                              hipStream_t stream) {
    const float* X     = (const float*)d_in[0];
    const int*   TS    = (const int*)d_in[1];
    // d_in[2] = attn_mask (causal) — recomputed on device
    const float* Wuvqk = (const float*)d_in[3];
    const float* buvqk = (const float*)d_in[4];
    const float* TB    = (const float*)d_in[5];
    const float* Wo    = (const float*)d_in[6];
    const float* bo    = (const float*)d_in[7];
    const float* rw    = (const float*)d_in[8];
    float* OUT = (float*)d_out;

    char* ws = (char*)d_ws;
    unsigned short* Qb  = (unsigned short*)(ws);               //  4 MiB [2][8][2048][64]
    unsigned short* Kb  = (unsigned short*)(ws + (4u << 20));  //  4 MiB
    unsigned short* Vt  = (unsigned short*)(ws + (8u << 20));  //  8 MiB [2][8][128][2048]
    unsigned short* Ub  = (unsigned short*)(ws + (16u << 20)); //  8 MiB [4096][1024]
    float*          Yb  = (float*)(ws + (24u << 20));          // 16 MiB [4096][1024] f32
    unsigned short* Xb  = (unsigned short*)(ws + (24u << 20)); //  8 MiB (aliases Yb; dead before attn)
    unsigned short* Wb  = (unsigned short*)(ws + (32u << 20)); //  6 MiB (aliases Yb tail)
    unsigned short* YP  = (unsigned short*)(ws + (40u << 20)); //  8 MiB [4096][1024]
    unsigned char*  BKm = (unsigned char*)(ws + (48u << 20));  //  8 MiB [2][2048][2048]
    unsigned short* Wob = (unsigned short*)(ws + (56u << 20)); //  2 MiB [1024][1024]

    cvt_bf16<<<8192, 256, 0, stream>>>(X, Wuvqk, Wo, Xb, Wb, Wob);
    bucketize<<<dim3(32, 32, 2), 256, 0, stream>>>(TS, BKm);
    gemm_uvqk<<<dim3(32, 24), 256, 0, stream>>>(Xb, Wb, buvqk, Ub, Vt, Qb, Kb);
    attn<<<dim3(16, 16), 512, 0, stream>>>(Qb, Kb, Vt, BKm, TB, Yb);
    rmsnorm_gate<<<4096, 256, 0, stream>>>(Yb, Ub, rw, YP);
    gemm_out<<<dim3(32, 8), 256, 0, stream>>>(YP, Wob, bo, OUT);
}

// Round 3
// 174.355 us; speedup vs baseline: 1.8074x; 1.8074x over previous
//
#include <hip/hip_runtime.h>
#include <hip/hip_bf16.h>

typedef float f32x4 __attribute__((ext_vector_type(4)));
typedef short s16x8 __attribute__((ext_vector_type(8)));
typedef unsigned short u16x4 __attribute__((ext_vector_type(4)));

__device__ __forceinline__ float bf2f(unsigned short u) {
    union { unsigned int i; float f; } x; x.i = ((unsigned int)u) << 16; return x.f;
}
__device__ __forceinline__ unsigned short f2bf(float f) {
    union { float f; unsigned int i; } x; x.f = f;
    unsigned int r = x.i + 0x7FFFu + ((x.i >> 16) & 1u);
    return (unsigned short)(r >> 16);
}
__device__ __forceinline__ float silu(float v) {
    return v / (1.f + __expf(-v));
}

#define GLDS16(gp, lp) __builtin_amdgcn_global_load_lds( \
    (const __attribute__((address_space(1))) unsigned int*)(gp), \
    (__attribute__((address_space(3))) unsigned int*)(lp), 16, 0, 0)

// ---------------------------------------------------------------------------
// Kernel 0: convert X / W_uvqk / W_o to bf16 (one pass, memory-bound)
// ---------------------------------------------------------------------------
__global__ __launch_bounds__(256) void cvt_bf16(
    const float* __restrict__ X, const float* __restrict__ W,
    const float* __restrict__ Wo,
    unsigned short* __restrict__ Xb, unsigned short* __restrict__ Wb,
    unsigned short* __restrict__ Wob)
{
    int idx = blockIdx.x * 256 + threadIdx.x;   // f32x4 chunk id, 2097152 total
    const float* src; unsigned short* dst; int off;
    if (idx < 1048576)       { src = X;  dst = Xb;  off = idx; }
    else if (idx < 1835008)  { src = W;  dst = Wb;  off = idx - 1048576; }
    else                     { src = Wo; dst = Wob; off = idx - 1835008; }
    f32x4 v = *reinterpret_cast<const f32x4*>(&src[(size_t)off * 4]);
    u16x4 o;
    #pragma unroll
    for (int j = 0; j < 4; ++j) o[j] = f2bf(v[j]);
    *reinterpret_cast<u16x4*>(&dst[(size_t)off * 4]) = o;
}

// ---------------------------------------------------------------------------
// Kernel 1: bucketize relative time -> byte matrix BK[b][i][j] (causal tiles)
// ---------------------------------------------------------------------------
__global__ __launch_bounds__(256) void bucketize(
    const int* __restrict__ TS, unsigned char* __restrict__ BK)
{
    const int jt = blockIdx.x, it = blockIdx.y, b = blockIdx.z;
    if (jt > it) return;                        // causal only
    __shared__ int bndRaw[63];
    __shared__ int bnd[64];
    __shared__ int tsi[64], tsj[64];
    const int tid = threadIdx.x;
    if (tid < 63) {
        double step = log(7776000.0) / 62.0;    // MAX_SPAN = 86400*90
        double v = exp(step * (double)tid);
        if (v < 1.0) v = 1.0;
        bndRaw[tid] = (int)floor(v);
    }
    if (tid >= 64 && tid < 128) tsi[tid - 64] = TS[b * 2048 + it * 64 + (tid - 64)];
    else if (tid >= 128 && tid < 192) tsj[tid - 128] = TS[b * 2048 + jt * 64 + (tid - 128)];
    __syncthreads();
    if (tid == 0) {                             // unique()
        int c = 0, p = -1;
        for (int i = 0; i < 63; ++i) { int x = bndRaw[i]; if (x != p) { bnd[c++] = x; p = x; } }
        for (; c < 64; ++c) bnd[c] = 0x7FFFFFFF;
    }
    __syncthreads();
    const int il = tid & 63, jc = (tid >> 6) * 16;
    const int tiv = tsi[il];
    unsigned char out[16];
    #pragma unroll
    for (int u = 0; u < 16; ++u) {
        int td = tiv - tsj[jc + u]; td = td < 0 ? -td : td; if (td < 1) td = 1;
        int pos = 0;
        #pragma unroll
        for (int st = 32; st; st >>= 1)
            if (bnd[pos + st - 1] < td) pos += st;
        out[u] = (unsigned char)pos;
    }
    *reinterpret_cast<int4*>(&BK[((size_t)b << 22) + (size_t)(it * 64 + il) * 2048 + jt * 64 + jc]) =
        *reinterpret_cast<const int4*>(out);
}

// ---------------------------------------------------------------------------
// Kernel 2: h = silu(Xb @ Wb^T + b); route into U, Vt, Q(*scale), K
// ---------------------------------------------------------------------------
__global__ __launch_bounds__(256) void gemm_uvqk(
    const unsigned short* __restrict__ Xb, const unsigned short* __restrict__ Wb,
    const float* __restrict__ bias,
    unsigned short* __restrict__ U, unsigned short* __restrict__ Vt,
    unsigned short* __restrict__ Q, unsigned short* __restrict__ K)
{
    __shared__ unsigned short sA[128][32];
    __shared__ unsigned short sB[128][32];
    const int tid = threadIdx.x;
    const int wv = tid >> 6, lane = tid & 63;
    const int g = lane >> 4, lr = lane & 15;
    const int m0 = blockIdx.x * 128, n0 = blockIdx.y * 128;
    const int wr = (wv >> 1) * 64, wc = (wv & 1) * 64;
    const int srow = (lane >> 2), scol = (lane & 3) * 8;   // staging lane layout
    f32x4 acc[4][4] = {};

    for (int k0 = 0; k0 < 1024; k0 += 32) {
        #pragma unroll
        for (int c = 0; c < 2; ++c) {
            int rb = (wv * 2 + c) * 16;
            GLDS16(&Xb[(size_t)(m0 + rb + srow) * 1024 + k0 + scol], &sA[rb][0]);
            GLDS16(&Wb[(size_t)(n0 + rb + srow) * 1024 + k0 + scol], &sB[rb][0]);
        }
        __syncthreads();
        s16x8 afr[4], bfr[4];
        #pragma unroll
        for (int i = 0; i < 4; ++i)
            afr[i] = *reinterpret_cast<const s16x8*>(&sA[wr + i * 16 + lr][g * 8]);
        #pragma unroll
        for (int i = 0; i < 4; ++i)
            bfr[i] = *reinterpret_cast<const s16x8*>(&sB[wc + i * 16 + lr][g * 8]);
        #pragma unroll
        for (int mi = 0; mi < 4; ++mi)
            #pragma unroll
            for (int ni = 0; ni < 4; ++ni)
                acc[mi][ni] = __builtin_amdgcn_mfma_f32_16x16x32_bf16(
                    afr[mi], bfr[ni], acc[mi][ni], 0, 0, 0);
        __syncthreads();
    }

    #pragma unroll
    for (int ni = 0; ni < 4; ++ni) {
        int n = n0 + wc + ni * 16 + lr;
        float bn = bias[n];
        #pragma unroll
        for (int mi = 0; mi < 4; ++mi) {
            #pragma unroll
            for (int r = 0; r < 4; ++r) {
                int m = m0 + wr + mi * 16 + g * 4 + r;
                float v = silu(acc[mi][ni][r] + bn);
                int b = m >> 11, l = m & 2047;
                if (n < 1024) {
                    U[(size_t)m * 1024 + n] = f2bf(v);
                } else if (n < 2048) {
                    int dd = n - 1024, h = dd >> 7, d = dd & 127;
                    Vt[(((size_t)(b * 8 + h) * 128 + d) << 11) + l] = f2bf(v);
                } else if (n < 2560) {
                    int dd = n - 2048, h = dd >> 6, d = dd & 63;
                    Q[((((size_t)(b * 8 + h) << 11) + l) << 6) + d] = f2bf(v * 0.125f);
                } else {
                    int dd = n - 2560, h = dd >> 6, d = dd & 63;
                    K[((((size_t)(b * 8 + h) << 11) + l) << 6) + d] = f2bf(v);
                }
            }
        }
    }
}

// ---------------------------------------------------------------------------
// Kernel 3: flash-style pointwise-silu attention.
// Block = 512 thr = 8 waves = one (bh, pair): waves 0-3 own tile x (16 rows
// each), waves 4-7 own tile 31-x. Lockstep j-loop; K/V tiles double-buffered
// in LDS via global_load_lds (pre-swizzled source + XOR-swizzled reads).
// Per-SIMD compute = (x+1) + (32-x) = 33 units — balanced for all x.
// ---------------------------------------------------------------------------
__global__ __launch_bounds__(512) void attn(
    const unsigned short* __restrict__ Q, const unsigned short* __restrict__ K,
    const unsigned short* __restrict__ Vt, const unsigned char* __restrict__ BK,
    const float* __restrict__ TB, float* __restrict__ Y)
{
    __shared__ unsigned short sK[2][64][64];    // 16 KiB, XOR-swizzled rows
    __shared__ unsigned short sV[2][128][64];   // 32 KiB, XOR-swizzled rows
    __shared__ unsigned short sP[8][16][72];    // per-wave P transpose
    __shared__ float tb[64];

    const int tid = threadIdx.x, wv = tid >> 6, lane = tid & 63;
    const int g = lane >> 4, lr = lane & 15;
    const int bh = blockIdx.y, b = bh >> 3, h = bh & 7;
    const int x = blockIdx.x;                   // pair id, 0..15
    const int my_ti = (wv < 4) ? x : 31 - x;
    const int jt_max = 31 - x;                  // longest j-range in the pair
    const int irow = my_ti * 64 + (wv & 3) * 16;

    if (tid < 64) tb[tid] = TB[tid * 8 + h];

    const unsigned short* qb = Q + ((size_t)bh << 11) * 64;
    const unsigned short* kb = K + ((size_t)bh << 11) * 64;
    const unsigned short* vtb = Vt + ((size_t)bh << 7) * 2048;
    const unsigned char* bkb = BK + ((size_t)b << 22);

    s16x8 aq[2];
    #pragma unroll
    for (int kk = 0; kk < 2; ++kk)
        aq[kk] = *reinterpret_cast<const s16x8*>(&qb[(size_t)(irow + lr) * 64 + kk * 32 + g * 8]);

    const unsigned char* bkr[4];
    #pragma unroll
    for (int r = 0; r < 4; ++r) bkr[r] = bkb + (size_t)(irow + g * 4 + r) * 2048;

    const int cs = lr & 7;                      // read-side XOR swizzle key

    // cooperative staging of K[64][64] + V[128][64] for tile jt into buffer bsel
    auto stage = [&](int jt, int bsel) {
        const int j0 = jt * 64;
        {   // K: 512 x 16B chunks, 1 per thread; pre-swizzle global source
            int row = tid >> 3, c8 = tid & 7;
            int c8s = c8 ^ (row & 7);
            GLDS16(&kb[(size_t)(j0 + row) * 64 + c8s * 8], &sK[bsel][row][c8 * 8]);
        }
        #pragma unroll
        for (int c = 0; c < 2; ++c) {           // V: 1024 chunks, 2 per thread
            int id = c * 512 + tid;
            int d = id >> 3, c8 = id & 7;
            int c8s = c8 ^ (d & 7);
            GLDS16(&vtb[(size_t)d * 2048 + j0 + c8s * 8], &sV[bsel][d][c8 * 8]);
        }
    };

    unsigned char bb[4][4];                     // bias bytes, prefetched 1 iter ahead
    stage(0, 0);
    #pragma unroll
    for (int ni = 0; ni < 4; ++ni)
        #pragma unroll
        for (int r = 0; r < 4; ++r) bb[ni][r] = bkr[r][ni * 16 + lr];

    f32x4 accy[8] = {};
    __syncthreads();

    int buf = 0;
    for (int jt = 0; jt <= jt_max; ++jt) {
        if (jt < jt_max) stage(jt + 1, buf ^ 1);
        if (jt <= my_ti) {
            const int j0 = jt * 64;
            float bias[4][4];
            #pragma unroll
            for (int ni = 0; ni < 4; ++ni)
                #pragma unroll
                for (int r = 0; r < 4; ++r) bias[ni][r] = tb[bb[ni][r]];
            if (jt < my_ti) {                   // prefetch next tile's bias bytes
                #pragma unroll
                for (int ni = 0; ni < 4; ++ni)
                    #pragma unroll
                    for (int r = 0; r < 4; ++r)
                        bb[ni][r] = bkr[r][j0 + 64 + ni * 16 + lr];
            }
            f32x4 s[4] = {};
            #pragma unroll
            for (int ni = 0; ni < 4; ++ni) {
                const int jl = ni * 16 + lr;
                #pragma unroll
                for (int kk = 0; kk < 2; ++kk) {
                    s16x8 bk = *reinterpret_cast<const s16x8*>(
                        (const char*)&sK[buf][0][0] + jl * 128 + (((kk * 4 + g) ^ cs) << 4));
                    s[ni] = __builtin_amdgcn_mfma_f32_16x16x32_bf16(aq[kk], bk, s[ni], 0, 0, 0);
                }
            }
            if (jt == my_ti) {                  // diagonal tile: causal mask bites
                #pragma unroll
                for (int ni = 0; ni < 4; ++ni) {
                    int j = j0 + ni * 16 + lr;
                    #pragma unroll
                    for (int r = 0; r < 4; ++r) {
                        int i = irow + g * 4 + r;
                        float v = silu(s[ni][r] + bias[ni][r]);
                        if (j > i) v = 0.f;
                        sP[wv][g * 4 + r][ni * 16 + lr] = f2bf(v);
                    }
                }
            } else {
                #pragma unroll
                for (int ni = 0; ni < 4; ++ni)
                    #pragma unroll
                    for (int r = 0; r < 4; ++r)
                        sP[wv][g * 4 + r][ni * 16 + lr] = f2bf(silu(s[ni][r] + bias[ni][r]));
            }
            s16x8 apv[2];
            #pragma unroll
            for (int kk = 0; kk < 2; ++kk)
                apv[kk] = *reinterpret_cast<const s16x8*>(&sP[wv][lr][kk * 32 + g * 8]);
            #pragma unroll
            for (int di = 0; di < 8; ++di) {
                const int dl = di * 16 + lr;
                #pragma unroll
                for (int kk = 0; kk < 2; ++kk) {
                    s16x8 bv = *reinterpret_cast<const s16x8*>(
                        (const char*)&sV[buf][0][0] + dl * 128 + (((kk * 4 + g) ^ cs) << 4));
                    accy[di] = __builtin_amdgcn_mfma_f32_16x16x32_bf16(apv[kk], bv, accy[di], 0, 0, 0);
                }
            }
        }
        __syncthreads();
        buf ^= 1;
    }

    #pragma unroll
    for (int di = 0; di < 8; ++di)
        #pragma unroll
        for (int r = 0; r < 4; ++r) {
            int i = irow + g * 4 + r;
            Y[(size_t)((b << 11) + i) * 1024 + h * 128 + di * 16 + lr] = accy[di][r];
        }
}

// ---------------------------------------------------------------------------
// Kernel 4: RMSNorm over HID=1024 then U-gate; emit bf16 YP.
// ---------------------------------------------------------------------------
__global__ __launch_bounds__(256) void rmsnorm_gate(
    const float* __restrict__ Y, const unsigned short* __restrict__ U,
    const float* __restrict__ rw, unsigned short* __restrict__ YP)
{
    __shared__ float red[4];
    const int row = blockIdx.x, tid = threadIdx.x;
    f32x4 v = *reinterpret_cast<const f32x4*>(&Y[(size_t)row * 1024 + tid * 4]);
    float ss = v[0] * v[0] + v[1] * v[1] + v[2] * v[2] + v[3] * v[3];
    #pragma unroll
    for (int off = 32; off; off >>= 1) ss += __shfl_down(ss, off);
    if ((tid & 63) == 0) red[tid >> 6] = ss;
    __syncthreads();
    float rms = rsqrtf((red[0] + red[1] + red[2] + red[3]) * (1.f / 1024.f) + 1e-6f);
    #pragma unroll
    for (int j = 0; j < 4; ++j) {
        int c = tid * 4 + j;
        float o = v[j] * rms * rw[c] * bf2f(U[(size_t)row * 1024 + c]);
        YP[(size_t)row * 1024 + c] = f2bf(o);
    }
}

// ---------------------------------------------------------------------------
// Kernel 5: OUT = YP @ Wob^T + b_o.
// ---------------------------------------------------------------------------
__global__ __launch_bounds__(256) void gemm_out(
    const unsigned short* __restrict__ YP, const unsigned short* __restrict__ Wob,
    const float* __restrict__ bo, float* __restrict__ OUT)
{
    __shared__ unsigned short sA[128][32];
    __shared__ unsigned short sB[128][32];
    const int tid = threadIdx.x;
    const int wv = tid >> 6, lane = tid & 63;
    const int g = lane >> 4, lr = lane & 15;
    const int m0 = blockIdx.x * 128, n0 = blockIdx.y * 128;
    const int wr = (wv >> 1) * 64, wc = (wv & 1) * 64;
    const int srow = (lane >> 2), scol = (lane & 3) * 8;
    f32x4 acc[4][4] = {};

    for (int k0 = 0; k0 < 1024; k0 += 32) {
        #pragma unroll
        for (int c = 0; c < 2; ++c) {
            int rb = (wv * 2 + c) * 16;
            GLDS16(&YP[(size_t)(m0 + rb + srow) * 1024 + k0 + scol], &sA[rb][0]);
            GLDS16(&Wob[(size_t)(n0 + rb + srow) * 1024 + k0 + scol], &sB[rb][0]);
        }
        __syncthreads();
        s16x8 afr[4], bfr[4];
        #pragma unroll
        for (int i = 0; i < 4; ++i)
            afr[i] = *reinterpret_cast<const s16x8*>(&sA[wr + i * 16 + lr][g * 8]);
        #pragma unroll
        for (int i = 0; i < 4; ++i)
            bfr[i] = *reinterpret_cast<const s16x8*>(&sB[wc + i * 16 + lr][g * 8]);
        #pragma unroll
        for (int mi = 0; mi < 4; ++mi)
            #pragma unroll
            for (int ni = 0; ni < 4; ++ni)
                acc[mi][ni] = __builtin_amdgcn_mfma_f32_16x16x32_bf16(
                    afr[mi], bfr[ni], acc[mi][ni], 0, 0, 0);
        __syncthreads();
    }

    #pragma unroll
    for (int ni = 0; ni < 4; ++ni) {
        int n = n0 + wc + ni * 16 + lr;
        float bn = bo[n];
        #pragma unroll
        for (int mi = 0; mi < 4; ++mi)
            #pragma unroll
            for (int r = 0; r < 4; ++r) {
                int m = m0 + wr + mi * 16 + g * 4 + r;
                OUT[(size_t)m * 1024 + n] = acc[mi][ni][r] + bn;
            }
    }
}

// ---------------------------------------------------------------------------
extern "C" void kernel_launch(void* const* d_in, const int* in_sizes, int n_in,
                              void* d_out, int out_size, void* d_ws, size_t ws_size,
                              hipStream_t stream) {
    const float* X     = (const float*)d_in[0];
    const int*   TS    = (const int*)d_in[1];
    // d_in[2] = attn_mask (causal) — recomputed on device
    const float* Wuvqk = (const float*)d_in[3];
    const float* buvqk = (const float*)d_in[4];
    const float* TB    = (const float*)d_in[5];
    const float* Wo    = (const float*)d_in[6];
    const float* bo    = (const float*)d_in[7];
    const float* rw    = (const float*)d_in[8];
    float* OUT = (float*)d_out;

    char* ws = (char*)d_ws;
    unsigned short* Qb  = (unsigned short*)(ws);               //  4 MiB [2][8][2048][64]
    unsigned short* Kb  = (unsigned short*)(ws + (4u << 20));  //  4 MiB
    unsigned short* Vt  = (unsigned short*)(ws + (8u << 20));  //  8 MiB [2][8][128][2048]
    unsigned short* Ub  = (unsigned short*)(ws + (16u << 20)); //  8 MiB [4096][1024]
    float*          Yb  = (float*)(ws + (24u << 20));          // 16 MiB [4096][1024] f32
    unsigned short* Xb  = (unsigned short*)(ws + (24u << 20)); //  8 MiB (aliases Yb; dead before attn)
    unsigned short* Wb  = (unsigned short*)(ws + (32u << 20)); //  6 MiB (aliases Yb tail)
    unsigned short* YP  = (unsigned short*)(ws + (40u << 20)); //  8 MiB [4096][1024]
    unsigned char*  BKm = (unsigned char*)(ws + (48u << 20));  //  8 MiB [2][2048][2048]
    unsigned short* Wob = (unsigned short*)(ws + (56u << 20)); //  2 MiB [1024][1024]

    cvt_bf16<<<8192, 256, 0, stream>>>(X, Wuvqk, Wo, Xb, Wb, Wob);
    bucketize<<<dim3(32, 32, 2), 256, 0, stream>>>(TS, BKm);
    gemm_uvqk<<<dim3(32, 24), 256, 0, stream>>>(Xb, Wb, buvqk, Ub, Vt, Qb, Kb);
    attn<<<dim3(16, 16), 512, 0, stream>>>(Qb, Kb, Vt, BKm, TB, Yb);
    rmsnorm_gate<<<4096, 256, 0, stream>>>(Yb, Ub, rw, YP);
    gemm_out<<<dim3(32, 8), 256, 0, stream>>>(YP, Wob, bo, OUT);
}

// Round 4
// 164.302 us; speedup vs baseline: 1.9180x; 1.0612x over previous
//
#include <hip/hip_runtime.h>
#include <hip/hip_bf16.h>

typedef float f32x4 __attribute__((ext_vector_type(4)));
typedef short s16x8 __attribute__((ext_vector_type(8)));
typedef short s16x4 __attribute__((ext_vector_type(4)));
typedef unsigned short u16x4 __attribute__((ext_vector_type(4)));

__device__ __forceinline__ float bf2f(unsigned short u) {
    union { unsigned int i; float f; } x; x.i = ((unsigned int)u) << 16; return x.f;
}
__device__ __forceinline__ unsigned short f2bf(float f) {
    union { float f; unsigned int i; } x; x.f = f;
    unsigned int r = x.i + 0x7FFFu + ((x.i >> 16) & 1u);
    return (unsigned short)(r >> 16);
}
__device__ __forceinline__ float silu(float v) {
    return v / (1.f + __expf(-v));
}

#define GLDS16(gp, lp) __builtin_amdgcn_global_load_lds( \
    (const __attribute__((address_space(1))) unsigned int*)(gp), \
    (__attribute__((address_space(3))) unsigned int*)(lp), 16, 0, 0)

// ---------------------------------------------------------------------------
// Kernel 0: convert X / W_uvqk / W_o to bf16 (one pass, memory-bound)
// ---------------------------------------------------------------------------
__global__ __launch_bounds__(256) void cvt_bf16(
    const float* __restrict__ X, const float* __restrict__ W,
    const float* __restrict__ Wo,
    unsigned short* __restrict__ Xb, unsigned short* __restrict__ Wb,
    unsigned short* __restrict__ Wob)
{
    int idx = blockIdx.x * 256 + threadIdx.x;   // f32x4 chunk id, 2097152 total
    const float* src; unsigned short* dst; int off;
    if (idx < 1048576)       { src = X;  dst = Xb;  off = idx; }
    else if (idx < 1835008)  { src = W;  dst = Wb;  off = idx - 1048576; }
    else                     { src = Wo; dst = Wob; off = idx - 1835008; }
    f32x4 v = *reinterpret_cast<const f32x4*>(&src[(size_t)off * 4]);
    u16x4 o;
    #pragma unroll
    for (int j = 0; j < 4; ++j) o[j] = f2bf(v[j]);
    *reinterpret_cast<u16x4*>(&dst[(size_t)off * 4]) = o;
}

// ---------------------------------------------------------------------------
// Kernel 1: bucketize relative time -> byte matrix BK[b][i][j] (causal tiles)
// ---------------------------------------------------------------------------
__global__ __launch_bounds__(256) void bucketize(
    const int* __restrict__ TS, unsigned char* __restrict__ BK)
{
    const int jt = blockIdx.x, it = blockIdx.y, b = blockIdx.z;
    if (jt > it) return;                        // causal only
    __shared__ int bndRaw[63];
    __shared__ int bnd[64];
    __shared__ int tsi[64], tsj[64];
    const int tid = threadIdx.x;
    if (tid < 63) {
        double step = log(7776000.0) / 62.0;    // MAX_SPAN = 86400*90
        double v = exp(step * (double)tid);
        if (v < 1.0) v = 1.0;
        bndRaw[tid] = (int)floor(v);
    }
    if (tid >= 64 && tid < 128) tsi[tid - 64] = TS[b * 2048 + it * 64 + (tid - 64)];
    else if (tid >= 128 && tid < 192) tsj[tid - 128] = TS[b * 2048 + jt * 64 + (tid - 128)];
    __syncthreads();
    if (tid == 0) {                             // unique()
        int c = 0, p = -1;
        for (int i = 0; i < 63; ++i) { int x = bndRaw[i]; if (x != p) { bnd[c++] = x; p = x; } }
        for (; c < 64; ++c) bnd[c] = 0x7FFFFFFF;
    }
    __syncthreads();
    const int il = tid & 63, jc = (tid >> 6) * 16;
    const int tiv = tsi[il];
    unsigned char out[16];
    #pragma unroll
    for (int u = 0; u < 16; ++u) {
        int td = tiv - tsj[jc + u]; td = td < 0 ? -td : td; if (td < 1) td = 1;
        int pos = 0;
        #pragma unroll
        for (int st = 32; st; st >>= 1)
            if (bnd[pos + st - 1] < td) pos += st;
        out[u] = (unsigned char)pos;
    }
    *reinterpret_cast<int4*>(&BK[((size_t)b << 22) + (size_t)(it * 64 + il) * 2048 + jt * 64 + jc]) =
        *reinterpret_cast<const int4*>(out);
}

// ---------------------------------------------------------------------------
// Kernel 2: h = silu(Xb @ Wb^T + b); route into U, Vt, Q(*scale), K
// XCD-swizzled 1D grid: each XCD owns 3 consecutive B-panels.
// ---------------------------------------------------------------------------
__global__ __launch_bounds__(256) void gemm_uvqk(
    const unsigned short* __restrict__ Xb, const unsigned short* __restrict__ Wb,
    const float* __restrict__ bias,
    unsigned short* __restrict__ U, unsigned short* __restrict__ Vt,
    unsigned short* __restrict__ Q, unsigned short* __restrict__ K)
{
    __shared__ unsigned short sA[128][32];
    __shared__ unsigned short sB[128][32];
    const int tid = threadIdx.x;
    const int wv = tid >> 6, lane = tid & 63;
    const int g = lane >> 4, lr = lane & 15;
    const int wid = (blockIdx.x & 7) * 96 + (blockIdx.x >> 3);   // 768 blocks
    const int m0 = (wid & 31) * 128, n0 = (wid >> 5) * 128;
    const int wr = (wv >> 1) * 64, wc = (wv & 1) * 64;
    const int srow = (lane >> 2), scol = (lane & 3) * 8;
    f32x4 acc[4][4] = {};

    for (int k0 = 0; k0 < 1024; k0 += 32) {
        #pragma unroll
        for (int c = 0; c < 2; ++c) {
            int rb = (wv * 2 + c) * 16;
            GLDS16(&Xb[(size_t)(m0 + rb + srow) * 1024 + k0 + scol], &sA[rb][0]);
            GLDS16(&Wb[(size_t)(n0 + rb + srow) * 1024 + k0 + scol], &sB[rb][0]);
        }
        __syncthreads();
        s16x8 afr[4], bfr[4];
        #pragma unroll
        for (int i = 0; i < 4; ++i)
            afr[i] = *reinterpret_cast<const s16x8*>(&sA[wr + i * 16 + lr][g * 8]);
        #pragma unroll
        for (int i = 0; i < 4; ++i)
            bfr[i] = *reinterpret_cast<const s16x8*>(&sB[wc + i * 16 + lr][g * 8]);
        #pragma unroll
        for (int mi = 0; mi < 4; ++mi)
            #pragma unroll
            for (int ni = 0; ni < 4; ++ni)
                acc[mi][ni] = __builtin_amdgcn_mfma_f32_16x16x32_bf16(
                    afr[mi], bfr[ni], acc[mi][ni], 0, 0, 0);
        __syncthreads();
    }

    #pragma unroll
    for (int ni = 0; ni < 4; ++ni) {
        int n = n0 + wc + ni * 16 + lr;
        float bn = bias[n];
        #pragma unroll
        for (int mi = 0; mi < 4; ++mi) {
            #pragma unroll
            for (int r = 0; r < 4; ++r) {
                int m = m0 + wr + mi * 16 + g * 4 + r;
                float v = silu(acc[mi][ni][r] + bn);
                int b = m >> 11, l = m & 2047;
                if (n < 1024) {
                    U[(size_t)m * 1024 + n] = f2bf(v);
                } else if (n < 2048) {
                    int dd = n - 1024, h = dd >> 7, d = dd & 127;
                    Vt[(((size_t)(b * 8 + h) * 128 + d) << 11) + l] = f2bf(v);
                } else if (n < 2560) {
                    int dd = n - 2048, h = dd >> 6, d = dd & 63;
                    Q[((((size_t)(b * 8 + h) << 11) + l) << 6) + d] = f2bf(v * 0.125f);
                } else {
                    int dd = n - 2560, h = dd >> 6, d = dd & 63;
                    K[((((size_t)(b * 8 + h) << 11) + l) << 6) + d] = f2bf(v);
                }
            }
        }
    }
}

// ---------------------------------------------------------------------------
// Kernel 3: pointwise-silu attention, swapped-QK^T (S^T), zero P-transpose.
// 256 thr = 4 waves = one 64-row i-tile. Grid 512, mapped so XCD k owns
// heads {2k,2k+1} (K/V L2-resident) and each CU gets the ti/(31-ti) pair.
// Counted-vmcnt double-buffered staging (K+V+BK bytes), raw s_barrier.
// ---------------------------------------------------------------------------
__global__ __launch_bounds__(256) void attn(
    const unsigned short* __restrict__ Q, const unsigned short* __restrict__ K,
    const unsigned short* __restrict__ Vt, const unsigned char* __restrict__ BK,
    const float* __restrict__ TB, float* __restrict__ Y)
{
    __shared__ __align__(16) unsigned short sK[2][64][64];    // 16 KiB
    __shared__ __align__(16) unsigned short sV[2][128][64];   // 32 KiB
    __shared__ __align__(16) unsigned char  sBK[2][64][64];   //  8 KiB
    __shared__ float tb[64];

    const int tid = threadIdx.x, wv = tid >> 6, lane = tid & 63;
    const int g = lane >> 4, lr = lane & 15;

    const int bid = blockIdx.x;
    const int xcd = bid & 7, slot = bid >> 3;
    const int s = slot & 31, p = s & 1, idx = s >> 1;
    const int bh = xcd * 2 + p;
    const int ti = (slot >= 32) ? (31 - idx) : idx;   // CU pairing: idx & 31-idx
    const int b = bh >> 3, h = bh & 7;
    const int i0 = ti * 64;
    const int irow = i0 + wv * 16;

    if (tid < 64) tb[tid] = TB[tid * 8 + h];

    const unsigned short* qb = Q + ((size_t)bh << 11) * 64;
    const unsigned short* kb = K + ((size_t)bh << 11) * 64;
    const unsigned short* vtb = Vt + ((size_t)bh << 7) * 2048;
    const unsigned char* bkb = BK + ((size_t)b << 22) + (size_t)i0 * 2048;

    // Q fragment (B-operand of swapped QK): lane holds Q[irow+lr][k]
    s16x8 aq[2];
    #pragma unroll
    for (int kk = 0; kk < 2; ++kk)
        aq[kk] = *reinterpret_cast<const s16x8*>(&qb[(size_t)(irow + lr) * 64 + kk * 32 + g * 8]);

    // cooperative staging: K 2 + V 4 + BK 1 = 7 glds insts per wave per tile
    auto stage = [&](int jt, int bsel) {
        const int j0 = jt * 64;
        #pragma unroll
        for (int c = 0; c < 2; ++c) {
            int id = c * 256 + tid;
            int row = id >> 3, c8 = id & 7;
            GLDS16(&kb[(size_t)(j0 + row) * 64 + ((c8 ^ (row & 7)) * 8)], &sK[bsel][row][c8 * 8]);
        }
        #pragma unroll
        for (int c = 0; c < 4; ++c) {
            int id = c * 256 + tid;
            int d = id >> 3, c8 = id & 7;
            GLDS16(&vtb[(size_t)d * 2048 + j0 + ((c8 ^ (d & 7)) * 8)], &sV[bsel][d][c8 * 8]);
        }
        {
            int row = tid >> 2, c16 = tid & 3;
            GLDS16(&bkb[(size_t)row * 2048 + j0 + ((c16 ^ (row & 3)) * 16)], &sBK[bsel][row][c16 * 16]);
        }
    };

    __syncthreads();                 // tb visible
    stage(0, 0);

    f32x4 accy[8] = {};
    const int cs = lr & 7;           // LDS read-side XOR swizzle key
    const int r3 = lr & 3;           // BK swizzle key (row&3 with row=wv*16+lr)
    const int ib = irow + lr;        // this lane's absolute i row

    for (int jt = 0; jt <= ti; ++jt) {
        const int buf = jt & 1;
        __builtin_amdgcn_s_barrier();            // prev compute done -> buf^1 free
        if (jt < ti) {
            stage(jt + 1, buf ^ 1);
            asm volatile("s_waitcnt vmcnt(7)" ::: "memory");   // tile jt landed
        } else {
            asm volatile("s_waitcnt vmcnt(0)" ::: "memory");
        }
        __builtin_amdgcn_s_barrier();            // all waves' tile jt visible

        const int j0 = jt * 64;
        // swapped QK^T: S^T[j][i] = mfma(A=K rows j, B=Q rows i)
        f32x4 sacc[4] = {};
        unsigned int bw[4];
        #pragma unroll
        for (int ni = 0; ni < 4; ++ni) {
            bw[ni] = *reinterpret_cast<const unsigned int*>(
                &sBK[buf][wv * 16 + lr][0] + (((ni ^ r3) * 16) + g * 4));
            const int jl = ni * 16 + lr;
            #pragma unroll
            for (int kk = 0; kk < 2; ++kk) {
                s16x8 kf = *reinterpret_cast<const s16x8*>(
                    (const char*)&sK[buf][0][0] + jl * 128 + (((kk * 4 + g) ^ cs) << 4));
                sacc[ni] = __builtin_amdgcn_mfma_f32_16x16x32_bf16(kf, aq[kk], sacc[ni], 0, 0, 0);
            }
        }
        // bias + silu + causal mask; pack P as 16x16x16 A-frags (k = 4g+r)
        s16x4 pf[4];
        #pragma unroll
        for (int ni = 0; ni < 4; ++ni) {
            float pv0, pv1, pv2, pv3;
            {
                float v0 = silu(sacc[ni][0] + tb[bw[ni] & 255]);
                float v1 = silu(sacc[ni][1] + tb[(bw[ni] >> 8) & 255]);
                float v2 = silu(sacc[ni][2] + tb[(bw[ni] >> 16) & 255]);
                float v3 = silu(sacc[ni][3] + tb[(bw[ni] >> 24) & 255]);
                int jbase = j0 + ni * 16 + g * 4;
                pv0 = (jbase + 0 > ib) ? 0.f : v0;
                pv1 = (jbase + 1 > ib) ? 0.f : v1;
                pv2 = (jbase + 2 > ib) ? 0.f : v2;
                pv3 = (jbase + 3 > ib) ? 0.f : v3;
            }
            unsigned int w0, w1;
            asm("v_cvt_pk_bf16_f32 %0, %1, %2" : "=v"(w0) : "v"(pv0), "v"(pv1));
            asm("v_cvt_pk_bf16_f32 %0, %1, %2" : "=v"(w1) : "v"(pv2), "v"(pv3));
            union { unsigned int u[2]; s16x4 v; } cvt;
            cvt.u[0] = w0; cvt.u[1] = w1;
            pf[ni] = cvt.v;
        }
        // PV: K=16 MFMAs, P straight from registers
        #pragma unroll
        for (int di = 0; di < 8; ++di) {
            const int row = di * 16 + lr;
            #pragma unroll
            for (int ni = 0; ni < 4; ++ni) {
                s16x4 vf = *reinterpret_cast<const s16x4*>(
                    (const char*)&sV[buf][0][0] + row * 128 +
                    (((2 * ni + (g >> 1)) ^ cs) << 4) + ((g & 1) << 3));
                accy[di] = __builtin_amdgcn_mfma_f32_16x16x16bf16_1k(pf[ni], vf, accy[di], 0, 0, 0);
            }
        }
    }

    #pragma unroll
    for (int di = 0; di < 8; ++di)
        #pragma unroll
        for (int r = 0; r < 4; ++r) {
            int i = irow + g * 4 + r;
            Y[(size_t)((b << 11) + i) * 1024 + h * 128 + di * 16 + lr] = accy[di][r];
        }
}

// ---------------------------------------------------------------------------
// Kernel 4: RMSNorm over HID=1024 then U-gate; emit bf16 YP.
// ---------------------------------------------------------------------------
__global__ __launch_bounds__(256) void rmsnorm_gate(
    const float* __restrict__ Y, const unsigned short* __restrict__ U,
    const float* __restrict__ rw, unsigned short* __restrict__ YP)
{
    __shared__ float red[4];
    const int row = blockIdx.x, tid = threadIdx.x;
    f32x4 v = *reinterpret_cast<const f32x4*>(&Y[(size_t)row * 1024 + tid * 4]);
    float ss = v[0] * v[0] + v[1] * v[1] + v[2] * v[2] + v[3] * v[3];
    #pragma unroll
    for (int off = 32; off; off >>= 1) ss += __shfl_down(ss, off);
    if ((tid & 63) == 0) red[tid >> 6] = ss;
    __syncthreads();
    float rms = rsqrtf((red[0] + red[1] + red[2] + red[3]) * (1.f / 1024.f) + 1e-6f);
    #pragma unroll
    for (int j = 0; j < 4; ++j) {
        int c = tid * 4 + j;
        float o = v[j] * rms * rw[c] * bf2f(U[(size_t)row * 1024 + c]);
        YP[(size_t)row * 1024 + c] = f2bf(o);
    }
}

// ---------------------------------------------------------------------------
// Kernel 5: OUT = YP @ Wob^T + b_o.  8 waves / 512 thr per 128x128 tile.
// XCD-swizzled: each XCD owns one B-panel (n-tile).
// ---------------------------------------------------------------------------
__global__ __launch_bounds__(512) void gemm_out(
    const unsigned short* __restrict__ YP, const unsigned short* __restrict__ Wob,
    const float* __restrict__ bo, float* __restrict__ OUT)
{
    __shared__ unsigned short sA[128][32];
    __shared__ unsigned short sB[128][32];
    const int tid = threadIdx.x;
    const int wv = tid >> 6, lane = tid & 63;
    const int g = lane >> 4, lr = lane & 15;
    const int wid = (blockIdx.x & 7) * 32 + (blockIdx.x >> 3);   // 256 blocks
    const int m0 = (wid & 31) * 128, n0 = (wid >> 5) * 128;
    const int wr = (wv >> 2) * 64, wc = (wv & 3) * 32;
    f32x4 acc[4][2] = {};

    const int srow = tid >> 2, scol = (tid & 3) * 8;

    for (int k0 = 0; k0 < 1024; k0 += 32) {
        GLDS16(&YP[(size_t)(m0 + srow) * 1024 + k0 + scol], &sA[srow][scol]);
        GLDS16(&Wob[(size_t)(n0 + srow) * 1024 + k0 + scol], &sB[srow][scol]);
        __syncthreads();
        s16x8 afr[4], bfr[2];
        #pragma unroll
        for (int i = 0; i < 4; ++i)
            afr[i] = *reinterpret_cast<const s16x8*>(&sA[wr + i * 16 + lr][g * 8]);
        #pragma unroll
        for (int i = 0; i < 2; ++i)
            bfr[i] = *reinterpret_cast<const s16x8*>(&sB[wc + i * 16 + lr][g * 8]);
        #pragma unroll
        for (int mi = 0; mi < 4; ++mi)
            #pragma unroll
            for (int ni = 0; ni < 2; ++ni)
                acc[mi][ni] = __builtin_amdgcn_mfma_f32_16x16x32_bf16(
                    afr[mi], bfr[ni], acc[mi][ni], 0, 0, 0);
        __syncthreads();
    }

    #pragma unroll
    for (int ni = 0; ni < 2; ++ni) {
        int n = n0 + wc + ni * 16 + lr;
        float bn = bo[n];
        #pragma unroll
        for (int mi = 0; mi < 4; ++mi)
            #pragma unroll
            for (int r = 0; r < 4; ++r) {
                int m = m0 + wr + mi * 16 + g * 4 + r;
                OUT[(size_t)m * 1024 + n] = acc[mi][ni][r] + bn;
            }
    }
}

// ---------------------------------------------------------------------------
extern "C" void kernel_launch(void* const* d_in, const int* in_sizes, int n_in,
                              void* d_out, int out_size, void* d_ws, size_t ws_size,
                              hipStream_t stream) {
    const float* X     = (const float*)d_in[0];
    const int*   TS    = (const int*)d_in[1];
    // d_in[2] = attn_mask (causal) — recomputed on device
    const float* Wuvqk = (const float*)d_in[3];
    const float* buvqk = (const float*)d_in[4];
    const float* TB    = (const float*)d_in[5];
    const float* Wo    = (const float*)d_in[6];
    const float* bo    = (const float*)d_in[7];
    const float* rw    = (const float*)d_in[8];
    float* OUT = (float*)d_out;

    char* ws = (char*)d_ws;
    unsigned short* Qb  = (unsigned short*)(ws);               //  4 MiB [2][8][2048][64]
    unsigned short* Kb  = (unsigned short*)(ws + (4u << 20));  //  4 MiB
    unsigned short* Vt  = (unsigned short*)(ws + (8u << 20));  //  8 MiB [2][8][128][2048]
    unsigned short* Ub  = (unsigned short*)(ws + (16u << 20)); //  8 MiB [4096][1024]
    float*          Yb  = (float*)(ws + (24u << 20));          // 16 MiB [4096][1024] f32
    unsigned short* Xb  = (unsigned short*)(ws + (24u << 20)); //  8 MiB (aliases Yb; dead before attn)
    unsigned short* Wb  = (unsigned short*)(ws + (32u << 20)); //  6 MiB (aliases Yb tail)
    unsigned short* YP  = (unsigned short*)(ws + (40u << 20)); //  8 MiB [4096][1024]
    unsigned char*  BKm = (unsigned char*)(ws + (48u << 20));  //  8 MiB [2][2048][2048]
    unsigned short* Wob = (unsigned short*)(ws + (56u << 20)); //  2 MiB [1024][1024]

    cvt_bf16<<<8192, 256, 0, stream>>>(X, Wuvqk, Wo, Xb, Wb, Wob);
    bucketize<<<dim3(32, 32, 2), 256, 0, stream>>>(TS, BKm);
    gemm_uvqk<<<768, 256, 0, stream>>>(Xb, Wb, buvqk, Ub, Vt, Qb, Kb);
    attn<<<512, 256, 0, stream>>>(Qb, Kb, Vt, BKm, TB, Yb);
    rmsnorm_gate<<<4096, 256, 0, stream>>>(Yb, Ub, rw, YP);
    gemm_out<<<256, 512, 0, stream>>>(YP, Wob, bo, OUT);
}